// Round 13
// baseline (2335.692 us; speedup 1.0000x reference)
//
#include <hip/hip_runtime.h>
#include <hip/hip_bf16.h>
#include <stdint.h>
#include <stddef.h>

// Problem sizes (fixed)
#define HID   1024
#define NB    64
#define SEQ   512
#define G3    3072   // 3*HID
#define EMB   512
#define LAT   64

typedef __attribute__((ext_vector_type(4))) float f32x4;
typedef __attribute__((ext_vector_type(8))) short bfrag;  // 8 bf16 (4 VGPRs)
typedef unsigned long long ull;

// ---------- helpers ----------
__device__ __forceinline__ unsigned short f2bf(float x) {   // RNE f32->bf16
  union { float f; unsigned u; } v; v.f = x;
  unsigned u = v.u + 0x7fffu + ((v.u >> 16) & 1u);
  return (unsigned short)(u >> 16);
}
__device__ __forceinline__ float bf2f(short s) {
  union { unsigned u; float f; } v; v.u = ((unsigned)(unsigned short)s) << 16;
  return v.f;
}
__device__ __forceinline__ float fsig(float x) {
  return 1.0f / (1.0f + __builtin_exp2f(-1.4426950408889634f * x));
}
__device__ __forceinline__ float ftanh(float x) {
  return 1.0f - 2.0f / (1.0f + __builtin_exp2f(2.8853900817779268f * x));
}
__device__ __forceinline__ void gload_lds16(const void* g, void* l) {
  __builtin_amdgcn_global_load_lds(
      (const __attribute__((address_space(1))) unsigned int*)g,
      (__attribute__((address_space(3))) unsigned int*)l, 16, 0, 0);
}

// ---------- kernel 0: w_ih f32 -> bf16 ----------
__global__ void cvt_wih_kernel(const float* __restrict__ in, short* __restrict__ out) {
  int i = (blockIdx.x * 256 + threadIdx.x) * 8;   // grid sized exactly
  f32x4 a = *(const f32x4*)(in + i);
  f32x4 b = *(const f32x4*)(in + i + 4);
  bfrag o;
  o[0]=(short)f2bf(a[0]); o[1]=(short)f2bf(a[1]); o[2]=(short)f2bf(a[2]); o[3]=(short)f2bf(a[3]);
  o[4]=(short)f2bf(b[0]); o[5]=(short)f2bf(b[1]); o[6]=(short)f2bf(b[2]); o[7]=(short)f2bf(b[3]);
  *(bfrag*)(out + i) = o;
}

// ---------- kernel 1: gx = emb[ids] @ w_ih^T  (bf16 MFMA, fp32 acc, bf16 out) ----------
__global__ void __launch_bounds__(256) gemm_gx_kernel(
    const int* __restrict__ ids, const float* __restrict__ emb,
    const short* __restrict__ wih, short* __restrict__ gx)
{
  const int nt = blockIdx.x, mt = blockIdx.y;
  const int tid = threadIdx.x;
  const int lane = tid & 63, wave = tid >> 6;
  const int wr = wave >> 1, wc = wave & 1;

  __shared__ __align__(16) short A_lds[128 * 48];
  __shared__ __align__(16) short B_lds[128 * 32];
  __shared__ int ids_s[128];

  if (tid < 128) ids_s[tid] = ids[mt * 128 + tid];
  __syncthreads();

  f32x4 acc[4][4];
  #pragma unroll
  for (int i = 0; i < 4; ++i)
    #pragma unroll
    for (int j = 0; j < 4; ++j) acc[i][j] = (f32x4){0.f, 0.f, 0.f, 0.f};

  const int r_stage = tid >> 1;
  const int kh = (tid & 1) * 16;

  #pragma unroll 1
  for (int kc = 0; kc < 16; ++kc) {
    __syncthreads();
    {
      const float* src = emb + (size_t)ids_s[r_stage] * 512 + kc * 32 + kh;
      f32x4 v0 = *(const f32x4*)(src);
      f32x4 v1 = *(const f32x4*)(src + 4);
      f32x4 v2 = *(const f32x4*)(src + 8);
      f32x4 v3 = *(const f32x4*)(src + 12);
      bfrag p0, p1;
      p0[0]=(short)f2bf(v0[0]); p0[1]=(short)f2bf(v0[1]); p0[2]=(short)f2bf(v0[2]); p0[3]=(short)f2bf(v0[3]);
      p0[4]=(short)f2bf(v1[0]); p0[5]=(short)f2bf(v1[1]); p0[6]=(short)f2bf(v1[2]); p0[7]=(short)f2bf(v1[3]);
      p1[0]=(short)f2bf(v2[0]); p1[1]=(short)f2bf(v2[1]); p1[2]=(short)f2bf(v2[2]); p1[3]=(short)f2bf(v2[3]);
      p1[4]=(short)f2bf(v3[0]); p1[5]=(short)f2bf(v3[1]); p1[6]=(short)f2bf(v3[2]); p1[7]=(short)f2bf(v3[3]);
      *(bfrag*)&A_lds[r_stage * 48 + kh]     = p0;
      *(bfrag*)&A_lds[r_stage * 48 + kh + 8] = p1;
    }
    {
      #pragma unroll
      for (int ii = 0; ii < 2; ++ii) {
        int i = wave * 2 + ii;
        const short* src = wih + (size_t)(nt * 128 + i * 16 + (lane >> 2)) * 512
                               + kc * 32 + (lane & 3) * 8;
        gload_lds16((const void*)src, (void*)&B_lds[i * 512]);
      }
    }
    asm volatile("s_waitcnt vmcnt(0)" ::: "memory");
    __syncthreads();

    bfrag a[4], b[4];
    #pragma unroll
    for (int mi = 0; mi < 4; ++mi)
      a[mi] = *(const bfrag*)&A_lds[(wr * 64 + mi * 16 + (lane & 15)) * 48 + (lane >> 4) * 8];
    #pragma unroll
    for (int ni = 0; ni < 4; ++ni)
      b[ni] = *(const bfrag*)&B_lds[(wc * 64 + ni * 16 + (lane & 15)) * 32 + (lane >> 4) * 8];
    #pragma unroll
    for (int mi = 0; mi < 4; ++mi)
      #pragma unroll
      for (int ni = 0; ni < 4; ++ni)
        acc[mi][ni] = __builtin_amdgcn_mfma_f32_16x16x32_bf16(a[mi], b[ni], acc[mi][ni], 0, 0, 0);
  }

  #pragma unroll
  for (int mi = 0; mi < 4; ++mi)
    #pragma unroll
    for (int ni = 0; ni < 4; ++ni)
      #pragma unroll
      for (int r = 0; r < 4; ++r) {
        int m = mt * 128 + wr * 64 + mi * 16 + (lane >> 4) * 4 + r;
        int n = nt * 128 + wc * 64 + ni * 16 + (lane & 15);
        gx[(size_t)m * G3 + n] = (short)f2bf(acc[mi][ni][r]);
      }
}

// ---------- kernel 2: persistent GRU scan — round-7 protocol, 32 cols/WG ----------
// 128 WGs x 512 thr (8 waves = 2 col-halves x 4 K-quarters). WG = (team = bid>>5
// owns 16 batch rows, cg2 = bid&31 owns 32 hidden cols). Halves the per-step IF
// broadcast (each WG stages the 32KB team h once -> 4MB/step grid-wide vs 8MB)
// and halves flag fan-out (32 flags/team). Per-wave weights wfrag[3][8] = 96
// VGPRs (16 cols x 3 gates x K/4) — identical fragment code to round 7.
// NOTE __launch_bounds__(512,1): (512,2) would cap VGPR at 128 and spill (r6).
__global__ void __launch_bounds__(512, 1) gru_scan_kernel(
    const short* __restrict__ gx, const float* __restrict__ whh,
    const float* __restrict__ bihp, const float* __restrict__ bhhp,
    ull* __restrict__ hbuf_q, unsigned int* __restrict__ flags,
    float* __restrict__ hsum)
{
  const int team = blockIdx.x >> 5;        // 0..3
  const int cg2  = blockIdx.x & 31;        // 32-col group
  const int tid  = threadIdx.x;            // 0..511
  const int lane = tid & 63, wv = tid >> 6;     // 8 waves
  const int ch   = wv >> 2;                // col-half 0..1
  const int kq   = wv & 3;                 // K-quarter 0..3
  const int bl   = lane & 15;
  const int bsub = (lane >> 4) * 4;
  const int jcol = cg2 * 32 + ch * 16 + bl;
  const int bteam = team * 16;

  __shared__ __align__(16) short h_lds[16 * 1024];     // 32 KB [b][k] swizzled
  __shared__ __align__(16) float part[2 * 3 * 3 * 256];// 18 KB [ch][g][kq-1][lane*4]
  __shared__ __align__(16) short hstg[16 * 32];        //  1 KB [b][c32]

  // --- weights: 16 cols x 3 gates x K-quarter as B-frags (bf16), 96 VGPRs ---
  bfrag wfrag[3][8];
  #pragma unroll
  for (int g = 0; g < 3; ++g) {
    const float* wrow = whh + (size_t)(g * 1024 + jcol) * 1024 + kq * 256 + (lane >> 4) * 8;
    #pragma unroll
    for (int ks = 0; ks < 8; ++ks) {
      const float* p = wrow + ks * 32;
      f32x4 lo = *(const f32x4*)p;
      f32x4 hi = *(const f32x4*)(p + 4);
      bfrag f;
      f[0]=(short)f2bf(lo[0]); f[1]=(short)f2bf(lo[1]); f[2]=(short)f2bf(lo[2]); f[3]=(short)f2bf(lo[3]);
      f[4]=(short)f2bf(hi[0]); f[5]=(short)f2bf(hi[1]); f[6]=(short)f2bf(hi[2]); f[7]=(short)f2bf(hi[3]);
      wfrag[g][ks] = f;
    }
  }
  float bih_r[3], bhh_r[3];
  #pragma unroll
  for (int g = 0; g < 3; ++g) {
    bih_r[g] = bihp[g * 1024 + jcol];
    bhh_r[g] = bhhp[g * 1024 + jcol];
  }

  float hprev[4] = {0.f, 0.f, 0.f, 0.f};
  float hacc[4]  = {0.f, 0.f, 0.f, 0.f};
  const int xorm = (bl & 7) << 4;
  const char* lbase = (const char*)h_lds + bl * 2048;
  unsigned int* fteam  = flags + team * 512;    // 32 flags, 64B (16 u32) apart
  unsigned int* myflag = fteam + cg2 * 16;

  // gx prefetch for current step (combiner waves kq==0, one per col-half)
  short gxr_[4][3];
  if (kq == 0) {
    #pragma unroll
    for (int r = 0; r < 4; ++r) {
      size_t base = ((size_t)(bteam + bsub + r) * SEQ + 0) * G3 + jcol;
      gxr_[r][0] = gx[base];
      gxr_[r][1] = gx[base + 1024];
      gxr_[r][2] = gx[base + 2048];
    }
  }

  #pragma unroll 1
  for (int s = 0; s < SEQ; ++s) {
    const ull* hsrc = hbuf_q + ((s & 1) ? 16384 : 0) + team * 4096;       // 4096 qwords
    ull*       hdst = hbuf_q + (((s + 1) & 1) ? 16384 : 0) + team * 4096;

    // 1. stage team h(s) -> LDS: 512 thr x 8 coalesced agent 8B loads,
    //    exchange layout [cg16][b][c4] -> LDS [b][k] with the XOR swizzle.
    {
      ull hv[8];
      #pragma unroll
      for (int j = 0; j < 8; ++j)
        hv[j] = __hip_atomic_load(hsrc + j * 512 + tid, __ATOMIC_RELAXED,
                                  __HIP_MEMORY_SCOPE_AGENT);
      #pragma unroll
      for (int j = 0; j < 8; ++j) {
        int q  = j * 512 + tid;
        int cgq = q >> 6, b = (q >> 2) & 15, cq = q & 3;
        *(ull*)((char*)h_lds + b * 2048 + ((cgq * 32 + cq * 8) ^ ((b & 7) << 4))) = hv[j];
      }
    }
    __syncthreads();   // S1

    // 2. partial gh over this wave's K-quarter for its col-half: 24 MFMAs
    f32x4 a0 = {0.f,0.f,0.f,0.f}, a1 = {0.f,0.f,0.f,0.f}, a2 = {0.f,0.f,0.f,0.f};
    #pragma unroll
    for (int ks = 0; ks < 8; ++ks) {
      int k2 = kq * 512 + ks * 64 + (lane >> 4) * 16;   // byte offset of k*2
      bfrag af = *(const bfrag*)(lbase + (k2 ^ xorm));
      a0 = __builtin_amdgcn_mfma_f32_16x16x32_bf16(af, wfrag[0][ks], a0, 0, 0, 0);
      a1 = __builtin_amdgcn_mfma_f32_16x16x32_bf16(af, wfrag[1][ks], a1, 0, 0, 0);
      a2 = __builtin_amdgcn_mfma_f32_16x16x32_bf16(af, wfrag[2][ks], a2, 0, 0, 0);
    }
    if (kq) {
      int w1 = kq - 1;
      *(f32x4*)&part[((ch * 9 + 0 * 3 + w1) * 64 + lane) * 4] = a0;
      *(f32x4*)&part[((ch * 9 + 1 * 3 + w1) * 64 + lane) * 4] = a1;
      *(f32x4*)&part[((ch * 9 + 2 * 3 + w1) * 64 + lane) * 4] = a2;
    }
    __syncthreads();   // S2

    // 3. combiner waves (kq==0, one per col-half): combine, gates, stage h_new
    if (kq == 0) {
      f32x4 s0 = a0, s1 = a1, s2 = a2;
      #pragma unroll
      for (int w1 = 0; w1 < 3; ++w1) {
        s0 += *(const f32x4*)&part[((ch * 9 + 0 * 3 + w1) * 64 + lane) * 4];
        s1 += *(const f32x4*)&part[((ch * 9 + 1 * 3 + w1) * 64 + lane) * 4];
        s2 += *(const f32x4*)&part[((ch * 9 + 2 * 3 + w1) * 64 + lane) * 4];
      }
      #pragma unroll
      for (int r = 0; r < 4; ++r) {
        float ghr = s0[r] + bhh_r[0];
        float ghz = s1[r] + bhh_r[1];
        float ghn = s2[r] + bhh_r[2];
        float rg = fsig(bf2f(gxr_[r][0]) + bih_r[0] + ghr);
        float zg = fsig(bf2f(gxr_[r][1]) + bih_r[1] + ghz);
        float ng = ftanh(bf2f(gxr_[r][2]) + bih_r[2] + rg * ghn);
        float hn = (1.f - zg) * ng + zg * hprev[r];
        hprev[r] = hn;
        hacc[r] += hn;
        hstg[(bsub + r) * 32 + ch * 16 + bl] = (short)f2bf(hn);
      }
    }
    __syncthreads();   // S3

    // 4. wave wv==1: TWO contiguous 512B agent bursts + drain + flag.
    //    combiners: prefetch next gx; wv==0 then direct-polls the 32 team flags.
    if (wv == 1) {
      const ull* hq = (const ull*)hstg;   // 128 qwords: [b][8] (b=j>>3, ch'=(j>>2)&1, c4=j&3)
      ull v0 = hq[(lane >> 2) * 8 + (lane & 3)];        // ch'=0 qwords
      ull v1 = hq[(lane >> 2) * 8 + 4 + (lane & 3)];    // ch'=1 qwords
      __hip_atomic_store(hdst + cg2 * 128 + lane,      v0, __ATOMIC_RELAXED,
                         __HIP_MEMORY_SCOPE_AGENT);
      __hip_atomic_store(hdst + cg2 * 128 + 64 + lane, v1, __ATOMIC_RELAXED,
                         __HIP_MEMORY_SCOPE_AGENT);
      asm volatile("s_waitcnt vmcnt(0)" ::: "memory");   // this wave's stores done
      if (lane == 0)
        __hip_atomic_store(myflag, (unsigned)(s + 1), __ATOMIC_RELAXED,
                           __HIP_MEMORY_SCOPE_AGENT);
    }
    if (kq == 0) {
      int sn = (s + 1 < SEQ) ? (s + 1) : s;
      #pragma unroll
      for (int r = 0; r < 4; ++r) {
        size_t base = ((size_t)(bteam + bsub + r) * SEQ + sn) * G3 + jcol;
        gxr_[r][0] = gx[base];
        gxr_[r][1] = gx[base + 1024];
        gxr_[r][2] = gx[base + 2048];
      }
    }
    if (wv == 0) {
      unsigned tgt = (unsigned)(s + 1);
      for (;;) {    // 32 flags, 64B apart; lanes 32-63 duplicate lanes 0-31
        unsigned v = __hip_atomic_load(fteam + (lane & 31) * 16, __ATOMIC_RELAXED,
                                       __HIP_MEMORY_SCOPE_AGENT);
        if (__all((int)(v >= tgt))) break;
      }
    }
    __syncthreads();   // S4
  }

  if (kq == 0) {
    #pragma unroll
    for (int r = 0; r < 4; ++r)
      hsum[(size_t)(bteam + bsub + r) * 1024 + jcol] = hacc[r] * (1.0f / 512.0f);
  }
}

// ---------- kernel 3: mean/logv projections (fp32) ----------
__global__ void proj_kernel(const float* __restrict__ hbar,
                            const float* __restrict__ wm, const float* __restrict__ bm,
                            const float* __restrict__ wl, const float* __restrict__ bl,
                            float* __restrict__ out)
{
  int b = blockIdx.x, t = threadIdx.x;  // 128 threads: 0-63 mean, 64-127 logv
  __shared__ float hrow[1024];
  for (int k = t; k < 1024; k += 128) hrow[k] = hbar[(size_t)b * 1024 + k];
  __syncthreads();
  int j = t & 63;
  const float* w = (t < 64) ? (wm + (size_t)j * 1024) : (wl + (size_t)j * 1024);
  float acc = (t < 64) ? bm[j] : bl[j];
  for (int k = 0; k < 1024; k += 4) {
    f32x4 wv = *(const f32x4*)(w + k);
    acc += hrow[k] * wv[0] + hrow[k+1] * wv[1] + hrow[k+2] * wv[2] + hrow[k+3] * wv[3];
  }
  out[(size_t)((t < 64) ? 0 : 4096) + b * 64 + j] = acc;
}

// ---------- launch ----------
extern "C" void kernel_launch(void* const* d_in, const int* in_sizes, int n_in,
                              void* d_out, int out_size, void* d_ws, size_t ws_size,
                              hipStream_t stream) {
  const int*   ids   = (const int*)d_in[0];
  const float* emb   = (const float*)d_in[1];
  const float* w_ih  = (const float*)d_in[2];
  const float* w_hh  = (const float*)d_in[3];
  const float* b_ih  = (const float*)d_in[4];
  const float* b_hh  = (const float*)d_in[5];
  const float* w_mean= (const float*)d_in[6];
  const float* b_mean= (const float*)d_in[7];
  const float* w_logv= (const float*)d_in[8];
  const float* b_logv= (const float*)d_in[9];
  float* out = (float*)d_out;

  char* ws = (char*)d_ws;
  // ws layout
  unsigned int* flags = (unsigned int*)(ws);                 //      8192 B (4 teams x 32 flags, 64B apart)
  ull* hbuf_q        = (ull*)(ws + 8192);                    //    262144 B [2][4][4096] qwords bf16 ([cg16][b][c4])
  float* hsum        = (float*)(ws + 8192 + 262144);         //    262144 B [64][1024] f32
  short* wihb        = (short*)(ws + 8192 + 262144 + 262144);           //   3145728 B
  short* gxbuf       = (short*)(ws + 8192 + 262144 + 262144 + 3145728); // 201326592 B

  // zero flags + h double-buffers (deterministic across graph replays)
  hipMemsetAsync(ws, 0, 8192 + 262144, stream);

  // 0: w_ih -> bf16
  cvt_wih_kernel<<<768, 256, 0, stream>>>(w_ih, wihb);
  // 1: gx GEMM
  gemm_gx_kernel<<<dim3(24, 256), 256, 0, stream>>>(ids, emb, wihb, gxbuf);
  // 2: persistent scan — 128 WGs x 512 thr (32 cols/WG): halved IF broadcast +
  //    halved flag fan-out. Co-resident (128 <= 256 CUs, 1 WG/CU).
  gru_scan_kernel<<<128, 512, 0, stream>>>(gxbuf, w_hh, b_ih, b_hh, hbuf_q, flags, hsum);
  // 3: projections
  proj_kernel<<<64, 128, 0, stream>>>(hsum, w_mean, b_mean, w_logv, b_logv, out);
}

// Round 14
// 1877.448 us; speedup vs baseline: 1.2441x; 1.2441x over previous
//
#include <hip/hip_runtime.h>
#include <hip/hip_bf16.h>
#include <stdint.h>
#include <stddef.h>

// Problem sizes (fixed)
#define HID   1024
#define NB    64
#define SEQ   512
#define G3    3072   // 3*HID
#define EMB   512
#define LAT   64

typedef __attribute__((ext_vector_type(4))) float f32x4;
typedef __attribute__((ext_vector_type(8))) short bfrag;  // 8 bf16 (4 VGPRs)
typedef unsigned long long ull;

// ---------- helpers ----------
__device__ __forceinline__ unsigned short f2bf(float x) {   // RNE f32->bf16
  union { float f; unsigned u; } v; v.f = x;
  unsigned u = v.u + 0x7fffu + ((v.u >> 16) & 1u);
  return (unsigned short)(u >> 16);
}
__device__ __forceinline__ float bf2f(short s) {
  union { unsigned u; float f; } v; v.u = ((unsigned)(unsigned short)s) << 16;
  return v.f;
}
__device__ __forceinline__ float fsig(float x) {
  return 1.0f / (1.0f + __builtin_exp2f(-1.4426950408889634f * x));
}
__device__ __forceinline__ float ftanh(float x) {
  return 1.0f - 2.0f / (1.0f + __builtin_exp2f(2.8853900817779268f * x));
}
__device__ __forceinline__ void gload_lds16(const void* g, void* l) {
  __builtin_amdgcn_global_load_lds(
      (const __attribute__((address_space(1))) unsigned int*)g,
      (__attribute__((address_space(3))) unsigned int*)l, 16, 0, 0);
}

// ---------- kernel 0: w_ih f32 -> bf16 ----------
__global__ void cvt_wih_kernel(const float* __restrict__ in, short* __restrict__ out) {
  int i = (blockIdx.x * 256 + threadIdx.x) * 8;   // grid sized exactly
  f32x4 a = *(const f32x4*)(in + i);
  f32x4 b = *(const f32x4*)(in + i + 4);
  bfrag o;
  o[0]=(short)f2bf(a[0]); o[1]=(short)f2bf(a[1]); o[2]=(short)f2bf(a[2]); o[3]=(short)f2bf(a[3]);
  o[4]=(short)f2bf(b[0]); o[5]=(short)f2bf(b[1]); o[6]=(short)f2bf(b[2]); o[7]=(short)f2bf(b[3]);
  *(bfrag*)(out + i) = o;
}

// ---------- kernel 1: gx = emb[ids] @ w_ih^T  (bf16 MFMA, fp32 acc, bf16 out) ----------
__global__ void __launch_bounds__(256) gemm_gx_kernel(
    const int* __restrict__ ids, const float* __restrict__ emb,
    const short* __restrict__ wih, short* __restrict__ gx)
{
  const int nt = blockIdx.x, mt = blockIdx.y;
  const int tid = threadIdx.x;
  const int lane = tid & 63, wave = tid >> 6;
  const int wr = wave >> 1, wc = wave & 1;

  __shared__ __align__(16) short A_lds[128 * 48];
  __shared__ __align__(16) short B_lds[128 * 32];
  __shared__ int ids_s[128];

  if (tid < 128) ids_s[tid] = ids[mt * 128 + tid];
  __syncthreads();

  f32x4 acc[4][4];
  #pragma unroll
  for (int i = 0; i < 4; ++i)
    #pragma unroll
    for (int j = 0; j < 4; ++j) acc[i][j] = (f32x4){0.f, 0.f, 0.f, 0.f};

  const int r_stage = tid >> 1;
  const int kh = (tid & 1) * 16;

  #pragma unroll 1
  for (int kc = 0; kc < 16; ++kc) {
    __syncthreads();
    {
      const float* src = emb + (size_t)ids_s[r_stage] * 512 + kc * 32 + kh;
      f32x4 v0 = *(const f32x4*)(src);
      f32x4 v1 = *(const f32x4*)(src + 4);
      f32x4 v2 = *(const f32x4*)(src + 8);
      f32x4 v3 = *(const f32x4*)(src + 12);
      bfrag p0, p1;
      p0[0]=(short)f2bf(v0[0]); p0[1]=(short)f2bf(v0[1]); p0[2]=(short)f2bf(v0[2]); p0[3]=(short)f2bf(v0[3]);
      p0[4]=(short)f2bf(v1[0]); p0[5]=(short)f2bf(v1[1]); p0[6]=(short)f2bf(v1[2]); p0[7]=(short)f2bf(v1[3]);
      p1[0]=(short)f2bf(v2[0]); p1[1]=(short)f2bf(v2[1]); p1[2]=(short)f2bf(v2[2]); p1[3]=(short)f2bf(v2[3]);
      p1[4]=(short)f2bf(v3[0]); p1[5]=(short)f2bf(v3[1]); p1[6]=(short)f2bf(v3[2]); p1[7]=(short)f2bf(v3[3]);
      *(bfrag*)&A_lds[r_stage * 48 + kh]     = p0;
      *(bfrag*)&A_lds[r_stage * 48 + kh + 8] = p1;
    }
    {
      #pragma unroll
      for (int ii = 0; ii < 2; ++ii) {
        int i = wave * 2 + ii;
        const short* src = wih + (size_t)(nt * 128 + i * 16 + (lane >> 2)) * 512
                               + kc * 32 + (lane & 3) * 8;
        gload_lds16((const void*)src, (void*)&B_lds[i * 512]);
      }
    }
    asm volatile("s_waitcnt vmcnt(0)" ::: "memory");
    __syncthreads();

    bfrag a[4], b[4];
    #pragma unroll
    for (int mi = 0; mi < 4; ++mi)
      a[mi] = *(const bfrag*)&A_lds[(wr * 64 + mi * 16 + (lane & 15)) * 48 + (lane >> 4) * 8];
    #pragma unroll
    for (int ni = 0; ni < 4; ++ni)
      b[ni] = *(const bfrag*)&B_lds[(wc * 64 + ni * 16 + (lane & 15)) * 32 + (lane >> 4) * 8];
    #pragma unroll
    for (int mi = 0; mi < 4; ++mi)
      #pragma unroll
      for (int ni = 0; ni < 4; ++ni)
        acc[mi][ni] = __builtin_amdgcn_mfma_f32_16x16x32_bf16(a[mi], b[ni], acc[mi][ni], 0, 0, 0);
  }

  #pragma unroll
  for (int mi = 0; mi < 4; ++mi)
    #pragma unroll
    for (int ni = 0; ni < 4; ++ni)
      #pragma unroll
      for (int r = 0; r < 4; ++r) {
        int m = mt * 128 + wr * 64 + mi * 16 + (lane >> 4) * 4 + r;
        int n = nt * 128 + wc * 64 + ni * 16 + (lane & 15);
        gx[(size_t)m * G3 + n] = (short)f2bf(acc[mi][ni][r]);
      }
}

// ---------- kernel 2: persistent GRU scan — r7 base, 2-barrier thin protocol ----------
// 256 WGs x 256 thr (4 waves). WG = (team = bid>>6 owns 16 batch rows,
// cg = bid&63 owns 16 hidden cols). Wave = K-quarter (wfrag[3][8] = 96 VGPRs).
// Thin protocol vs r7:
//  - wave kq polls ONLY the 16 flags of writers cg in [16kq,16kq+16) (its own
//    quarter), then stages its own quarter into its own LDS region -> no S1/S4.
//  - only S2 (partials ready) and S3 (hstg ready) barriers remain.
//  - wave1's publish+drain+flag overlaps other waves' poll+stage; S2 joins.
// Race audit: part write(s+1) is post-S3(s) >= post-combine-read(s); hstg
// overwrite(s+1) is post-S2(s+1) >= post-publish-read(s); buffer parity WAR
// safe (consuming h(s) proves all h(s-1) reads done); polls acyclic.
__global__ void __launch_bounds__(256, 1) gru_scan_kernel(
    const short* __restrict__ gx, const float* __restrict__ whh,
    const float* __restrict__ bihp, const float* __restrict__ bhhp,
    ull* __restrict__ hbuf_q, unsigned int* __restrict__ flags,
    float* __restrict__ hsum)
{
  const int wg   = blockIdx.x;       // 0..255
  const int team = wg >> 6;          // 0..3
  const int cg   = wg & 63;          // col-group
  const int tid  = threadIdx.x;
  const int lane = tid & 63, wave = tid >> 6;   // wave = K-quarter 0..3
  const int bl   = lane & 15;
  const int bsub = (lane >> 4) * 4;
  const int jcol = cg * 16 + bl;
  const int bteam = team * 16;

  __shared__ __align__(16) short h_lds[16 * 1024];   // 32 KB [b][k] swizzled
  __shared__ __align__(16) float part[3 * 3 * 256];  // 9 KB [g][wave-1][lane*4]
  __shared__ __align__(16) short hstg[256];          // 512 B [b][c] exchange order

  // --- weights: 16 cols x 3 gates x K-quarter as B-frags (bf16), 96 VGPRs ---
  bfrag wfrag[3][8];
  #pragma unroll
  for (int g = 0; g < 3; ++g) {
    const float* wrow = whh + (size_t)(g * 1024 + jcol) * 1024 + wave * 256 + (lane >> 4) * 8;
    #pragma unroll
    for (int ks = 0; ks < 8; ++ks) {
      const float* p = wrow + ks * 32;
      f32x4 lo = *(const f32x4*)p;
      f32x4 hi = *(const f32x4*)(p + 4);
      bfrag f;
      f[0]=(short)f2bf(lo[0]); f[1]=(short)f2bf(lo[1]); f[2]=(short)f2bf(lo[2]); f[3]=(short)f2bf(lo[3]);
      f[4]=(short)f2bf(hi[0]); f[5]=(short)f2bf(hi[1]); f[6]=(short)f2bf(hi[2]); f[7]=(short)f2bf(hi[3]);
      wfrag[g][ks] = f;
    }
  }
  float bih_r[3], bhh_r[3];
  #pragma unroll
  for (int g = 0; g < 3; ++g) {
    bih_r[g] = bihp[g * 1024 + jcol];
    bhh_r[g] = bhhp[g * 1024 + jcol];
  }

  float hprev[4] = {0.f, 0.f, 0.f, 0.f};
  float hacc[4]  = {0.f, 0.f, 0.f, 0.f};
  const int xorm = (bl & 7) << 4;
  const char* lbase = (const char*)h_lds + bl * 2048;
  unsigned int* fteam  = flags + team * 1024;     // 64 flags, 64B (16 u32) apart
  unsigned int* myflag = fteam + cg * 16;
  unsigned int* fq     = fteam + (wave * 16 + (lane & 15)) * 16;  // my quarter's 16 flags

  // wave-private staging constants: wave stages exchange qwords
  // q = wave*1024 + j*64 + lane  (cg = wave*16 + j, b = lane>>2, c4 = lane&3)
  const int st_b  = lane >> 2;
  const int st_c4 = lane & 3;
  char* const st_base = (char*)h_lds + st_b * 2048;
  const int st_swz = (st_b & 7) << 4;

  // gx prefetch for step 0 (wave 0 = combiner)
  short gxr_[4][3];
  if (wave == 0) {
    #pragma unroll
    for (int r = 0; r < 4; ++r) {
      size_t base = ((size_t)(bteam + bsub + r) * SEQ + 0) * G3 + jcol;
      gxr_[r][0] = gx[base];
      gxr_[r][1] = gx[base + 1024];
      gxr_[r][2] = gx[base + 2048];
    }
  }

  #pragma unroll 1
  for (int s = 0; s < SEQ; ++s) {
    const ull* hsrc = hbuf_q + ((s & 1) ? 16384 : 0) + team * 4096;       // 4096 qwords
    ull*       hdst = hbuf_q + (((s + 1) & 1) ? 16384 : 0) + team * 4096;

    // 1. per-wave poll: my quarter's 16 writer flags >= s (s=0 trivially true)
    {
      unsigned tgt = (unsigned)s;
      for (;;) {
        unsigned v = __hip_atomic_load(fq, __ATOMIC_RELAXED, __HIP_MEMORY_SCOPE_AGENT);
        if (__all((int)(v >= tgt))) break;
      }
    }

    // 2. stage MY K-quarter -> my LDS region (16 coalesced agent 8B loads)
    {
      ull hv[16];
      #pragma unroll
      for (int j = 0; j < 16; ++j)
        hv[j] = __hip_atomic_load(hsrc + wave * 1024 + j * 64 + lane,
                                  __ATOMIC_RELAXED, __HIP_MEMORY_SCOPE_AGENT);
      #pragma unroll
      for (int j = 0; j < 16; ++j) {
        int cgq = wave * 16 + j;
        *(ull*)(st_base + ((cgq * 32 + st_c4 * 8) ^ st_swz)) = hv[j];
      }
    }

    // 3. partial gh over this wave's K-quarter: 24 MFMAs (own LDS region only)
    f32x4 a0 = {0.f,0.f,0.f,0.f}, a1 = {0.f,0.f,0.f,0.f}, a2 = {0.f,0.f,0.f,0.f};
    #pragma unroll
    for (int ks = 0; ks < 8; ++ks) {
      int k2 = wave * 512 + ks * 64 + (lane >> 4) * 16;   // byte offset of k*2
      bfrag af = *(const bfrag*)(lbase + (k2 ^ xorm));
      a0 = __builtin_amdgcn_mfma_f32_16x16x32_bf16(af, wfrag[0][ks], a0, 0, 0, 0);
      a1 = __builtin_amdgcn_mfma_f32_16x16x32_bf16(af, wfrag[1][ks], a1, 0, 0, 0);
      a2 = __builtin_amdgcn_mfma_f32_16x16x32_bf16(af, wfrag[2][ks], a2, 0, 0, 0);
    }
    if (wave) {
      int w1 = wave - 1;
      *(f32x4*)&part[((0 * 3 + w1) * 64 + lane) * 4] = a0;
      *(f32x4*)&part[((1 * 3 + w1) * 64 + lane) * 4] = a1;
      *(f32x4*)&part[((2 * 3 + w1) * 64 + lane) * 4] = a2;
    }
    __syncthreads();   // S2: partials ready

    // 4. wave 0: combine K-quarters, gates (fp32), stage h_new in LDS
    if (wave == 0) {
      f32x4 s0 = a0, s1 = a1, s2 = a2;
      #pragma unroll
      for (int w1 = 0; w1 < 3; ++w1) {
        s0 += *(const f32x4*)&part[((0 * 3 + w1) * 64 + lane) * 4];
        s1 += *(const f32x4*)&part[((1 * 3 + w1) * 64 + lane) * 4];
        s2 += *(const f32x4*)&part[((2 * 3 + w1) * 64 + lane) * 4];
      }
      #pragma unroll
      for (int r = 0; r < 4; ++r) {
        float ghr = s0[r] + bhh_r[0];
        float ghz = s1[r] + bhh_r[1];
        float ghn = s2[r] + bhh_r[2];
        float rg = fsig(bf2f(gxr_[r][0]) + bih_r[0] + ghr);
        float zg = fsig(bf2f(gxr_[r][1]) + bih_r[1] + ghz);
        float ng = ftanh(bf2f(gxr_[r][2]) + bih_r[2] + rg * ghn);
        float hn = (1.f - zg) * ng + zg * hprev[r];
        hprev[r] = hn;
        hacc[r] += hn;
        hstg[(bsub + r) * 16 + bl] = (short)f2bf(hn);   // exchange order [b][c]
      }
    }
    __syncthreads();   // S3: hstg ready

    // 5. wave 1: ONE contiguous 512B agent burst + drain + flag (overlaps the
    //    other waves' next-step polls — no joining barrier needed).
    if (wave == 1) {
      ull v = ((const ull*)hstg)[lane];
      __hip_atomic_store(hdst + cg * 64 + lane, v, __ATOMIC_RELAXED,
                         __HIP_MEMORY_SCOPE_AGENT);
      asm volatile("s_waitcnt vmcnt(0)" ::: "memory");   // this wave's stores done
      if (lane == 0)
        __hip_atomic_store(myflag, (unsigned)(s + 1), __ATOMIC_RELAXED,
                           __HIP_MEMORY_SCOPE_AGENT);
    }
    // wave 0: prefetch next step's gx (in flight across the next poll; drained
    // at next S2 at the latest)
    if (wave == 0) {
      int sn = (s + 1 < SEQ) ? (s + 1) : s;
      #pragma unroll
      for (int r = 0; r < 4; ++r) {
        size_t base = ((size_t)(bteam + bsub + r) * SEQ + sn) * G3 + jcol;
        gxr_[r][0] = gx[base];
        gxr_[r][1] = gx[base + 1024];
        gxr_[r][2] = gx[base + 2048];
      }
    }
    // no S4: next iteration's per-wave poll gates everything.
  }

  if (wave == 0) {
    #pragma unroll
    for (int r = 0; r < 4; ++r)
      hsum[(size_t)(bteam + bsub + r) * 1024 + jcol] = hacc[r] * (1.0f / 512.0f);
  }
}

// ---------- kernel 3: mean/logv projections (fp32) ----------
__global__ void proj_kernel(const float* __restrict__ hbar,
                            const float* __restrict__ wm, const float* __restrict__ bm,
                            const float* __restrict__ wl, const float* __restrict__ bl,
                            float* __restrict__ out)
{
  int b = blockIdx.x, t = threadIdx.x;  // 128 threads: 0-63 mean, 64-127 logv
  __shared__ float hrow[1024];
  for (int k = t; k < 1024; k += 128) hrow[k] = hbar[(size_t)b * 1024 + k];
  __syncthreads();
  int j = t & 63;
  const float* w = (t < 64) ? (wm + (size_t)j * 1024) : (wl + (size_t)j * 1024);
  float acc = (t < 64) ? bm[j] : bl[j];
  for (int k = 0; k < 1024; k += 4) {
    f32x4 wv = *(const f32x4*)(w + k);
    acc += hrow[k] * wv[0] + hrow[k+1] * wv[1] + hrow[k+2] * wv[2] + hrow[k+3] * wv[3];
  }
  out[(size_t)((t < 64) ? 0 : 4096) + b * 64 + j] = acc;
}

// ---------- launch ----------
extern "C" void kernel_launch(void* const* d_in, const int* in_sizes, int n_in,
                              void* d_out, int out_size, void* d_ws, size_t ws_size,
                              hipStream_t stream) {
  const int*   ids   = (const int*)d_in[0];
  const float* emb   = (const float*)d_in[1];
  const float* w_ih  = (const float*)d_in[2];
  const float* w_hh  = (const float*)d_in[3];
  const float* b_ih  = (const float*)d_in[4];
  const float* b_hh  = (const float*)d_in[5];
  const float* w_mean= (const float*)d_in[6];
  const float* b_mean= (const float*)d_in[7];
  const float* w_logv= (const float*)d_in[8];
  const float* b_logv= (const float*)d_in[9];
  float* out = (float*)d_out;

  char* ws = (char*)d_ws;
  // ws layout
  unsigned int* flags = (unsigned int*)(ws);                 //     16384 B (4 teams x 64 flags, 64B apart)
  ull* hbuf_q        = (ull*)(ws + 16384);                   //    262144 B [2][4][4096] qwords bf16 ([cg][b][c4])
  float* hsum        = (float*)(ws + 16384 + 262144);        //    262144 B [64][1024] f32
  short* wihb        = (short*)(ws + 16384 + 262144 + 262144);           //   3145728 B
  short* gxbuf       = (short*)(ws + 16384 + 262144 + 262144 + 3145728); // 201326592 B

  // zero flags + h double-buffers (deterministic across graph replays)
  hipMemsetAsync(ws, 0, 16384 + 262144, stream);

  // 0: w_ih -> bf16
  cvt_wih_kernel<<<768, 256, 0, stream>>>(w_ih, wihb);
  // 1: gx GEMM
  gemm_gx_kernel<<<dim3(24, 256), 256, 0, stream>>>(ids, emb, wihb, gxbuf);
  // 2: persistent scan — 256 WGs x 256 thr, thin 2-barrier protocol with
  //    per-wave quarter polls/staging. All WGs co-resident.
  gru_scan_kernel<<<256, 256, 0, stream>>>(gxbuf, w_hh, b_ih, b_hh, hbuf_q, flags, hsum);
  // 3: projections
  proj_kernel<<<64, 128, 0, stream>>>(hsum, w_mean, b_mean, w_logv, b_logv, out);
}